// Round 1
// baseline (170.461 us; speedup 1.0000x reference)
//
#include <hip/hip_runtime.h>
#include <math.h>

typedef _Float16 f16;
typedef __attribute__((ext_vector_type(8))) _Float16 f16x8;
typedef __attribute__((ext_vector_type(4))) _Float16 f16x4;
typedef __attribute__((ext_vector_type(4))) float f32x4;

#define MFMA(a, b, c) __builtin_amdgcn_mfma_f32_16x16x32_f16((a), (b), (c), 0, 0, 0)

__device__ __forceinline__ void gld16(const f16* g, f16* l) {
  __builtin_amdgcn_global_load_lds(
      (const __attribute__((address_space(1))) unsigned int*)g,
      (__attribute__((address_space(3))) unsigned int*)l, 16, 0, 0);
}

__device__ __forceinline__ f16x8 pack8(const float* src) {
  float4 f0 = *(const float4*)src;
  float4 f1 = *(const float4*)(src + 4);
  f16x8 v;
  v[0] = (f16)f0.x; v[1] = (f16)f0.y; v[2] = (f16)f0.z; v[3] = (f16)f0.w;
  v[4] = (f16)f1.x; v[5] = (f16)f1.y; v[6] = (f16)f1.z; v[7] = (f16)f1.w;
  return v;
}

// ---------------- prep: ew = exp(wbias) as f16 [4096][4096] ----------------
__global__ __launch_bounds__(256) void prep_ew(const float* __restrict__ wb,
                                               f16* __restrict__ ew) {
  const size_t stride = (size_t)gridDim.x * 256;
  const size_t total = (size_t)4096 * 4096 / 4;
  for (size_t i = (size_t)blockIdx.x * 256 + threadIdx.x; i < total; i += stride) {
    float4 f = ((const float4*)wb)[i];
    f16x4 o;
    o.x = (f16)expf(f.x); o.y = (f16)expf(f.y);
    o.z = (f16)expf(f.z); o.w = (f16)expf(f.w);
    ((f16x4*)ew)[i] = o;
  }
}

// ---------------- prep: cast weights to f16 ----------------
// wqb [64][512]; wkvb [128][512] (wk rows 0-63, wv rows 64-127); wpb [512][64]
__global__ __launch_bounds__(256) void prep_w(const float* __restrict__ wq,
                                              const float* __restrict__ wk,
                                              const float* __restrict__ wv,
                                              const float* __restrict__ wp,
                                              f16* __restrict__ wqb,
                                              f16* __restrict__ wkvb,
                                              f16* __restrict__ wpb) {
  int i = blockIdx.x * 256 + threadIdx.x;  // grid = 128 -> i in [0, 32768)
  wqb[i] = (f16)wq[i];
  wkvb[i] = (f16)wk[i];
  wkvb[32768 + i] = (f16)wv[i];
  wpb[i] = (f16)wp[i];
}

// ---------------- k1_q: sigQ[m][h] = sigmoid(x@wq^T + bq), fp16 out ----------------
// BT-GEMM: A = x [32768][512] (f32, cast on stage), B = wqb [64][512]. BM=64, BN=64, BK=64.
__global__ __launch_bounds__(256) void k1_q(const float* __restrict__ x,
                                            const f16* __restrict__ wqb,
                                            const float* __restrict__ bq,
                                            f16* __restrict__ sigQ) {
  __shared__ alignas(16) f16 sAx[64 * 64];
  __shared__ alignas(16) f16 sBw[64 * 64];
  const int tid = threadIdx.x;
  const int wave = tid >> 6, lane = tid & 63;
  const int m0 = blockIdx.x * 64;
  const int sc = (tid & 7) * 8;

  f32x4 acc[4];
#pragma unroll
  for (int j = 0; j < 4; ++j) acc[j] = (f32x4){0.f, 0.f, 0.f, 0.f};

  for (int ks = 0; ks < 512; ks += 64) {
    // stage x tile [64][64] f32 -> f16 LDS
#pragma unroll
    for (int u = 0; u < 2; ++u) {
      int un = tid + u * 256;
      int r = un >> 3, c = (un & 7) * 8;
      *(f16x8*)&sAx[r * 64 + c] = pack8(x + (size_t)(m0 + r) * 512 + ks + c);
    }
    // stage wq tile [64][64] via global_load_lds
#pragma unroll
    for (int q = 0; q < 2; ++q) {
      int r = q * 32 + (tid >> 3);
      gld16(wqb + (size_t)r * 512 + ks + sc, &sBw[r * 64 + sc]);
    }
    __syncthreads();
#pragma unroll
    for (int kk = 0; kk < 2; ++kk) {
      const int ko = kk * 32 + (lane >> 4) * 8;
      f16x8 af = *(const f16x8*)&sAx[(wave * 16 + (lane & 15)) * 64 + ko];
#pragma unroll
      for (int j = 0; j < 4; ++j) {
        f16x8 bfr = *(const f16x8*)&sBw[(j * 16 + (lane & 15)) * 64 + ko];
        acc[j] = MFMA(af, bfr, acc[j]);
      }
    }
    __syncthreads();
  }
#pragma unroll
  for (int j = 0; j < 4; ++j) {
    const int n = j * 16 + (lane & 15);
    const float bqv = bq[n];
#pragma unroll
    for (int r = 0; r < 4; ++r) {
      const int m = m0 + wave * 16 + (lane >> 4) * 4 + r;
      const float v = acc[j][r] + bqv;
      sigQ[(size_t)m * 64 + n] = (f16)(1.f / (1.f + expf(-v)));
    }
  }
}

// ---------------- k1_kv: X_T[p][t] = eK*V (rows 0-511), eK (rows 512-1023) ----------------
// Output-transposed GEMM: C'[n][m] = sum_k wkv[n][k] * x[m][k]. Block: 128 weight rows x 64 cols.
__global__ __launch_bounds__(256) void k1_kv(const float* __restrict__ x,
                                             const f16* __restrict__ wkvb,
                                             const float* __restrict__ bk,
                                             const float* __restrict__ bv,
                                             f16* __restrict__ XT) {
  __shared__ alignas(16) f16 sAw[128 * 64];
  __shared__ alignas(16) f16 sBx[64 * 64];
  const int tid = threadIdx.x;
  const int wave = tid >> 6, lane = tid & 63;
  const int m0 = blockIdx.x * 64;  // x-row (b,t) tile
  const int sc = (tid & 7) * 8;

  f32x4 accK[4], accV[4];
#pragma unroll
  for (int j = 0; j < 4; ++j) {
    accK[j] = (f32x4){0.f, 0.f, 0.f, 0.f};
    accV[j] = (f32x4){0.f, 0.f, 0.f, 0.f};
  }

  for (int ks = 0; ks < 512; ks += 64) {
#pragma unroll
    for (int q = 0; q < 4; ++q) {
      int r = q * 32 + (tid >> 3);
      gld16(wkvb + (size_t)r * 512 + ks + sc, &sAw[r * 64 + sc]);
    }
#pragma unroll
    for (int u = 0; u < 2; ++u) {
      int un = tid + u * 256;
      int r = un >> 3, c = (un & 7) * 8;
      *(f16x8*)&sBx[r * 64 + c] = pack8(x + (size_t)(m0 + r) * 512 + ks + c);
    }
    __syncthreads();
#pragma unroll
    for (int kk = 0; kk < 2; ++kk) {
      const int ko = kk * 32 + (lane >> 4) * 8;
      f16x8 aK = *(const f16x8*)&sAw[(wave * 16 + (lane & 15)) * 64 + ko];
      f16x8 aV = *(const f16x8*)&sAw[(64 + wave * 16 + (lane & 15)) * 64 + ko];
#pragma unroll
      for (int j = 0; j < 4; ++j) {
        f16x8 bx = *(const f16x8*)&sBx[(j * 16 + (lane & 15)) * 64 + ko];
        accK[j] = MFMA(aK, bx, accK[j]);
        accV[j] = MFMA(aV, bx, accV[j]);
      }
    }
    __syncthreads();
  }
  const int b = m0 >> 12;
  const int t0 = m0 & 4095;
#pragma unroll
  for (int r = 0; r < 4; ++r) {
    const int h = wave * 16 + (lane >> 4) * 4 + r;
    const float bkv = bk[h], bvv = bv[h];
    const size_t rowKV = (size_t)(b * 64 + h) * 4096;
    const size_t rowK = (size_t)(512 + b * 64 + h) * 4096;
#pragma unroll
    for (int j = 0; j < 4; ++j) {
      const int t = t0 + j * 16 + (lane & 15);
      const float ek = expf(accK[j][r] + bkv);
      const float ev = accV[j][r] + bvv;
      XT[rowKV + t] = (f16)(ek * ev);
      XT[rowK + t] = (f16)ek;
    }
  }
}

// ---------------- k2_big: C[4096][1024] = ew[4096][4096] @ XT^T ----------------
// BT-GEMM, BM=BN=128, BK=64, 512 threads (8 waves, 4x2), double-buffered LDS.
__global__ __launch_bounds__(512) void k2_big(const f16* __restrict__ A,
                                              const f16* __restrict__ Bm,
                                              float* __restrict__ C) {
  __shared__ alignas(16) f16 sA[2][128 * 64];
  __shared__ alignas(16) f16 sB[2][128 * 64];
  const int tid = threadIdx.x;
  const int wave = tid >> 6, lane = tid & 63;
  const int m0 = blockIdx.x * 128;  // 32
  const int n0 = blockIdx.y * 128;  // 8
  const int wm = (wave >> 1) * 32;
  const int wn = (wave & 1) * 64;
  const int srow = tid >> 3;        // 0..63
  const int scol = (tid & 7) * 8;

  f32x4 acc[2][4];
#pragma unroll
  for (int i = 0; i < 2; ++i)
#pragma unroll
    for (int j = 0; j < 4; ++j) acc[i][j] = (f32x4){0.f, 0.f, 0.f, 0.f};

#define K2_STAGE(buf, ks)                                                                     \
  do {                                                                                        \
    gld16(A + (size_t)(m0 + srow) * 4096 + (ks) + scol, &sA[buf][srow * 64 + scol]);          \
    gld16(A + (size_t)(m0 + 64 + srow) * 4096 + (ks) + scol,                                  \
          &sA[buf][(64 + srow) * 64 + scol]);                                                 \
    gld16(Bm + (size_t)(n0 + srow) * 4096 + (ks) + scol, &sB[buf][srow * 64 + scol]);         \
    gld16(Bm + (size_t)(n0 + 64 + srow) * 4096 + (ks) + scol,                                 \
          &sB[buf][(64 + srow) * 64 + scol]);                                                 \
  } while (0)

  K2_STAGE(0, 0);
  __syncthreads();
  const int nk = 4096 / 64;
  for (int t = 0; t < nk; ++t) {
    const int buf = t & 1;
    if (t + 1 < nk) K2_STAGE(buf ^ 1, (t + 1) * 64);
#pragma unroll
    for (int kk = 0; kk < 2; ++kk) {
      const int ko = kk * 32 + (lane >> 4) * 8;
      f16x8 af[2], bfr[4];
#pragma unroll
      for (int i = 0; i < 2; ++i)
        af[i] = *(const f16x8*)&sA[buf][(wm + i * 16 + (lane & 15)) * 64 + ko];
#pragma unroll
      for (int j = 0; j < 4; ++j)
        bfr[j] = *(const f16x8*)&sB[buf][(wn + j * 16 + (lane & 15)) * 64 + ko];
#pragma unroll
      for (int i = 0; i < 2; ++i)
#pragma unroll
        for (int j = 0; j < 4; ++j) acc[i][j] = MFMA(af[i], bfr[j], acc[i][j]);
    }
    __syncthreads();
  }
#undef K2_STAGE
#pragma unroll
  for (int i = 0; i < 2; ++i) {
    const int row = m0 + wm + i * 16 + (lane >> 4) * 4;
#pragma unroll
    for (int j = 0; j < 4; ++j) {
      const int col = n0 + wn + j * 16 + (lane & 15);
#pragma unroll
      for (int r = 0; r < 4; ++r) C[(size_t)(row + r) * 1024 + col] = acc[i][j][r];
    }
  }
}

// ---------------- k3_yt: Yt[m][h] = sigQ * num / den (fp16 out) ----------------
__global__ __launch_bounds__(256) void k3_yt(const f16* __restrict__ sigQ,
                                             const float* __restrict__ C,
                                             f16* __restrict__ Yt) {
  const int wave = threadIdx.x >> 6, lane = threadIdx.x & 63;
  const int m = blockIdx.x * 4 + wave;
  const int b = m >> 12, t = m & 4095;
  const float sq = (float)sigQ[(size_t)m * 64 + lane];
  const float num = C[(size_t)t * 1024 + b * 64 + lane];
  const float den = C[(size_t)t * 1024 + 512 + b * 64 + lane];
  Yt[(size_t)m * 64 + lane] = (f16)(sq * num / den);
}

// ---------------- k4_out: out[m][d] = Yt @ wp^T + bp (f32 out) ----------------
// BT-GEMM: A = Yt [32768][64], B = wpb [512][64], K=64 single step. BM=BN=128.
__global__ __launch_bounds__(256) void k4_out(const f16* __restrict__ Yt,
                                              const f16* __restrict__ wpb,
                                              const float* __restrict__ bp,
                                              float* __restrict__ out) {
  __shared__ alignas(16) f16 sA[128 * 64];
  __shared__ alignas(16) f16 sB[128 * 64];
  const int tid = threadIdx.x;
  const int wave = tid >> 6, lane = tid & 63;
  const int m0 = blockIdx.x * 128;  // 256
  const int n0 = blockIdx.y * 128;  // 4
  const int wm = (wave >> 1) * 64;
  const int wn = (wave & 1) * 64;
  const int sc = (tid & 7) * 8;

#pragma unroll
  for (int q = 0; q < 4; ++q) {
    int r = q * 32 + (tid >> 3);
    gld16(Yt + (size_t)(m0 + r) * 64 + sc, &sA[r * 64 + sc]);
    gld16(wpb + (size_t)(n0 + r) * 64 + sc, &sB[r * 64 + sc]);
  }
  __syncthreads();

  f32x4 acc[4][4];
#pragma unroll
  for (int i = 0; i < 4; ++i)
#pragma unroll
    for (int j = 0; j < 4; ++j) acc[i][j] = (f32x4){0.f, 0.f, 0.f, 0.f};

#pragma unroll
  for (int kk = 0; kk < 2; ++kk) {
    const int ko = kk * 32 + (lane >> 4) * 8;
    f16x8 af[4], bfr[4];
#pragma unroll
    for (int i = 0; i < 4; ++i)
      af[i] = *(const f16x8*)&sA[(wm + i * 16 + (lane & 15)) * 64 + ko];
#pragma unroll
    for (int j = 0; j < 4; ++j)
      bfr[j] = *(const f16x8*)&sB[(wn + j * 16 + (lane & 15)) * 64 + ko];
#pragma unroll
    for (int i = 0; i < 4; ++i)
#pragma unroll
      for (int j = 0; j < 4; ++j) acc[i][j] = MFMA(af[i], bfr[j], acc[i][j]);
  }

#pragma unroll
  for (int i = 0; i < 4; ++i) {
    const int row = m0 + wm + i * 16 + (lane >> 4) * 4;
#pragma unroll
    for (int j = 0; j < 4; ++j) {
      const int col = n0 + wn + j * 16 + (lane & 15);
      const float bpv = bp[col];
#pragma unroll
      for (int r = 0; r < 4; ++r)
        out[(size_t)(row + r) * 512 + col] = acc[i][j][r] + bpv;
    }
  }
}

extern "C" void kernel_launch(void* const* d_in, const int* in_sizes, int n_in,
                              void* d_out, int out_size, void* d_ws, size_t ws_size,
                              hipStream_t stream) {
  const float* x = (const float*)d_in[0];
  const float* wq = (const float*)d_in[1];
  const float* bq = (const float*)d_in[2];
  const float* wk = (const float*)d_in[3];
  const float* bk = (const float*)d_in[4];
  const float* wv = (const float*)d_in[5];
  const float* bv = (const float*)d_in[6];
  const float* wp = (const float*)d_in[7];
  const float* bp = (const float*)d_in[8];
  const float* wbias = (const float*)d_in[9];
  float* out = (float*)d_out;

  char* ws = (char*)d_ws;
  f16* ew = (f16*)(ws);                       // 33,554,432 B
  f16* XT = (f16*)(ws + 33554432);            //  8,388,608 B
  f16* sigQ = (f16*)(ws + 41943040);          //  4,194,304 B
  float* Cnd = (float*)(ws + 46137344);       // 16,777,216 B
  f16* Yt = (f16*)(ws + 62914560);            //  4,194,304 B
  f16* wqb = (f16*)(ws + 67108864);           //     65,536 B
  f16* wkvb = (f16*)(ws + 67174400);          //    131,072 B
  f16* wpb = (f16*)(ws + 67305472);           //     65,536 B  (end: 67,371,008)

  prep_ew<<<4096, 256, 0, stream>>>(wbias, ew);
  prep_w<<<128, 256, 0, stream>>>(wq, wk, wv, wp, wqb, wkvb, wpb);
  k1_q<<<512, 256, 0, stream>>>(x, wqb, bq, sigQ);
  k1_kv<<<512, 256, 0, stream>>>(x, wkvb, bk, bv, XT);
  k2_big<<<dim3(32, 8), 512, 0, stream>>>(ew, XT, Cnd);
  k3_yt<<<8192, 256, 0, stream>>>(sigQ, Cnd, Yt);
  k4_out<<<dim3(256, 4), 256, 0, stream>>>(Yt, wpb, bp, out);
}

// Round 2
// 117.941 us; speedup vs baseline: 1.4453x; 1.4453x over previous
//
#include <hip/hip_runtime.h>
#include <math.h>

typedef _Float16 f16;
typedef __attribute__((ext_vector_type(8))) _Float16 f16x8;
typedef __attribute__((ext_vector_type(4))) _Float16 f16x4;
typedef __attribute__((ext_vector_type(4))) float f32x4;
typedef __attribute__((ext_vector_type(16))) float f32x16;

#define MFMA16(a, b, c) __builtin_amdgcn_mfma_f32_16x16x32_f16((a), (b), (c), 0, 0, 0)
#define MFMA32(a, b, c) __builtin_amdgcn_mfma_f32_32x32x16_f16((a), (b), (c), 0, 0, 0)

__device__ __forceinline__ void gld16(const f16* g, f16* l) {
  __builtin_amdgcn_global_load_lds(
      (const __attribute__((address_space(1))) unsigned int*)g,
      (__attribute__((address_space(3))) unsigned int*)l, 16, 0, 0);
}

__device__ __forceinline__ f16x8 pack8(const float* src) {
  float4 f0 = *(const float4*)src;
  float4 f1 = *(const float4*)(src + 4);
  f16x8 v;
  v[0] = (f16)f0.x; v[1] = (f16)f0.y; v[2] = (f16)f0.z; v[3] = (f16)f0.w;
  v[4] = (f16)f1.x; v[5] = (f16)f1.y; v[6] = (f16)f1.z; v[7] = (f16)f1.w;
  return v;
}

// ---------------- prep: ew = exp(wbias) as f16 [4096][4096] ----------------
__global__ __launch_bounds__(256) void prep_ew(const float* __restrict__ wb,
                                               f16* __restrict__ ew) {
  const size_t stride = (size_t)gridDim.x * 256;
  const size_t total = (size_t)4096 * 4096 / 4;
  for (size_t i = (size_t)blockIdx.x * 256 + threadIdx.x; i < total; i += stride) {
    float4 f = ((const float4*)wb)[i];
    f16x4 o;
    o.x = (f16)expf(f.x); o.y = (f16)expf(f.y);
    o.z = (f16)expf(f.z); o.w = (f16)expf(f.w);
    ((f16x4*)ew)[i] = o;
  }
}

// ---------------- prep: cast weights to f16 ----------------
// wqkvb [192][512]: rows 0-63 = wk, 64-127 = wv, 128-191 = wq. wpb [512][64].
__global__ __launch_bounds__(256) void prep_w(const float* __restrict__ wq,
                                              const float* __restrict__ wk,
                                              const float* __restrict__ wv,
                                              const float* __restrict__ wp,
                                              f16* __restrict__ wqkvb,
                                              f16* __restrict__ wpb) {
  int i = blockIdx.x * 256 + threadIdx.x;  // grid = 128 -> i in [0, 32768)
  wqkvb[i] = (f16)wk[i];
  wqkvb[32768 + i] = (f16)wv[i];
  wqkvb[65536 + i] = (f16)wq[i];
  wpb[i] = (f16)wp[i];
}

// ---------------- k1_qkv: sigQ[m][h], XT[b*128+h][t]=eK*V, XT[b*128+64+h][t]=eK --------
// One pass over x. 256 thr, 4 waves, BM=64 x-rows, BK=64.
__global__ __launch_bounds__(256) void k1_qkv(const float* __restrict__ x,
                                              const f16* __restrict__ wqkvb,
                                              const float* __restrict__ bq,
                                              const float* __restrict__ bk,
                                              const float* __restrict__ bv,
                                              f16* __restrict__ sigQ,
                                              f16* __restrict__ XT) {
  __shared__ alignas(16) f16 sW[192 * 64];
  __shared__ alignas(16) f16 sX[64 * 64];
  const int tid = threadIdx.x;
  const int wave = tid >> 6, lane = tid & 63;
  const int m0 = blockIdx.x * 64;
  const int l15 = lane & 15;

  f32x4 accQ[4], accK[4], accV[4];
#pragma unroll
  for (int j = 0; j < 4; ++j) {
    accQ[j] = (f32x4){0.f, 0.f, 0.f, 0.f};
    accK[j] = (f32x4){0.f, 0.f, 0.f, 0.f};
    accV[j] = (f32x4){0.f, 0.f, 0.f, 0.f};
  }

  const int sc8 = tid & 7;
  const int wr8 = (tid >> 3) & 7;
  const int wcol = (sc8 ^ wr8) * 8;  // swizzled source col (elements)

  for (int ks = 0; ks < 512; ks += 64) {
    // stage weights [192][64] via global_load_lds, source pre-swizzled
#pragma unroll
    for (int q = 0; q < 6; ++q) {
      int r = q * 32 + (tid >> 3);
      gld16(wqkvb + (size_t)r * 512 + ks + wcol, &sW[r * 64 + sc8 * 8]);
    }
    // stage x tile [64][64] f32->f16, swizzled ds_write
#pragma unroll
    for (int u = 0; u < 2; ++u) {
      int un = tid + u * 256;
      int r = un >> 3, c8 = un & 7;
      *(f16x8*)&sX[r * 64 + ((c8 ^ (r & 7)) * 8)] =
          pack8(x + (size_t)(m0 + r) * 512 + ks + c8 * 8);
    }
    __syncthreads();
#pragma unroll
    for (int kk = 0; kk < 2; ++kk) {
      const int c = kk * 4 + (lane >> 4);
      const int rK = wave * 16 + l15;
      const int rV = 64 + rK;
      f16x8 aK = *(const f16x8*)&sW[rK * 64 + ((c ^ (rK & 7)) * 8)];
      f16x8 aV = *(const f16x8*)&sW[rV * 64 + ((c ^ (rV & 7)) * 8)];
      f16x8 aQ = *(const f16x8*)&sX[rK * 64 + ((c ^ (rK & 7)) * 8)];
#pragma unroll
      for (int j = 0; j < 4; ++j) {
        const int rX = j * 16 + l15;
        const int rWq = 128 + j * 16 + l15;
        f16x8 bx = *(const f16x8*)&sX[rX * 64 + ((c ^ (rX & 7)) * 8)];
        f16x8 bw = *(const f16x8*)&sW[rWq * 64 + ((c ^ (rWq & 7)) * 8)];
        accK[j] = MFMA16(aK, bx, accK[j]);
        accV[j] = MFMA16(aV, bx, accV[j]);
        accQ[j] = MFMA16(aQ, bw, accQ[j]);
      }
    }
    __syncthreads();
  }
  const int b = m0 >> 12, t0 = m0 & 4095;
  // Q epilogue: sigmoid -> sigQ[m][h]
#pragma unroll
  for (int j = 0; j < 4; ++j) {
    const int h = j * 16 + l15;
    const float bqv = bq[h];
#pragma unroll
    for (int r = 0; r < 4; ++r) {
      const int m = m0 + wave * 16 + (lane >> 4) * 4 + r;
      const float v = accQ[j][r] + bqv;
      sigQ[(size_t)m * 64 + h] = (f16)(1.f / (1.f + expf(-v)));
    }
  }
  // K/V epilogue (transposed): XT rows b*128+h (eK*V), b*128+64+h (eK)
#pragma unroll
  for (int r = 0; r < 4; ++r) {
    const int h = wave * 16 + (lane >> 4) * 4 + r;
    const float bkv = bk[h], bvv = bv[h];
    const size_t rowKV = (size_t)(b * 128 + h) * 4096;
    const size_t rowK = (size_t)(b * 128 + 64 + h) * 4096;
#pragma unroll
    for (int j = 0; j < 4; ++j) {
      const int t = t0 + j * 16 + l15;
      const float ek = expf(accK[j][r] + bkv);
      const float ev = accV[j][r] + bvv;
      XT[rowKV + t] = (f16)(ek * ev);
      XT[rowK + t] = (f16)ek;
    }
  }
}

// ---------------- k2_big: Yt = sigQ * (ew@num^T)/(ew@den^T), fused ----------------
// 512 thr, 8 waves. BM=128 t-rows x (64 num + 64 den cols) for one batch. BK=128,
// in-block K-split: waves 0-3 k-half 0, waves 4-7 k-half 1; merge via LDS.
// Wave tile 64x64 via mfma_f32_32x32x16_f16. Swizzled LDS (chunk ^= row&7).
__global__ __launch_bounds__(512, 2) void k2_big(const f16* __restrict__ A,
                                                 const f16* __restrict__ Bm,
                                                 const f16* __restrict__ sigQ,
                                                 f16* __restrict__ Yt) {
  __shared__ alignas(16) f16 sA[2][128 * 128];
  __shared__ alignas(16) f16 sB[2][128 * 128];
  const int tid = threadIdx.x;
  const int wave = tid >> 6, lane = tid & 63;
  const int kh = wave >> 2;            // k-half
  const int wq = wave & 3;
  const int wr = wq >> 1, wc = wq & 1;
  const int bid = blockIdx.x;
  const int b = bid & 7;               // batch -> XCD L2 panel
  const int m0 = (bid >> 3) * 128;
  const f16* Bbase = Bm + (size_t)(b * 128) * 4096;

  const int srow = tid >> 4;           // 0..31
  const int sc16 = tid & 15;           // chunk 0..15
  const int gcol = ((sc16 ^ (srow & 7)) * 8);  // pre-swizzled source col

  f32x16 acc[2][2];
#pragma unroll
  for (int i = 0; i < 2; ++i)
#pragma unroll
    for (int j = 0; j < 2; ++j)
#pragma unroll
      for (int r = 0; r < 16; ++r) acc[i][j][r] = 0.f;

#define K2_STAGE(buf, ks)                                                              \
  do {                                                                                 \
    _Pragma("unroll") for (int q = 0; q < 4; ++q) {                                    \
      int r = q * 32 + srow;                                                           \
      gld16(A + (size_t)(m0 + r) * 4096 + (ks) + gcol, &sA[buf][r * 128 + sc16 * 8]);  \
      gld16(Bbase + (size_t)r * 4096 + (ks) + gcol, &sB[buf][r * 128 + sc16 * 8]);     \
    }                                                                                  \
  } while (0)

  K2_STAGE(0, 0);
  __syncthreads();
  const int rA0 = wr * 64 + (lane & 31);
  const int rB0 = wc * 32 + (lane & 31);
  const int nk = 4096 / 128;
  for (int t = 0; t < nk; ++t) {
    const int buf = t & 1;
    if (t + 1 < nk) K2_STAGE(buf ^ 1, (t + 1) * 128);
#pragma unroll
    for (int kk = 0; kk < 4; ++kk) {
      const int c = kh * 8 + kk * 2 + (lane >> 5);
      const int cx = (c ^ (rA0 & 7)) * 8;  // rA0&7 == rB0&7 == lane&7; +32/+64 keep &7
      f16x8 a0 = *(const f16x8*)&sA[buf][rA0 * 128 + cx];
      f16x8 a1 = *(const f16x8*)&sA[buf][(rA0 + 32) * 128 + cx];
      f16x8 b0 = *(const f16x8*)&sB[buf][rB0 * 128 + cx];
      f16x8 b1 = *(const f16x8*)&sB[buf][(rB0 + 64) * 128 + cx];
      acc[0][0] = MFMA32(a0, b0, acc[0][0]);
      acc[0][1] = MFMA32(a0, b1, acc[0][1]);
      acc[1][0] = MFMA32(a1, b0, acc[1][0]);
      acc[1][1] = MFMA32(a1, b1, acc[1][1]);
    }
    __syncthreads();
  }
#undef K2_STAGE

  // merge k-halves through LDS (reuse sA region: 16 tiles x 4KB = 64KB)
  float* red = (float*)sA;
  if (kh == 1) {
#pragma unroll
    for (int i = 0; i < 2; ++i)
#pragma unroll
      for (int j = 0; j < 2; ++j)
#pragma unroll
        for (int r = 0; r < 16; ++r)
          red[(((wq * 2 + i) * 2 + j) << 10) + (r << 6) + lane] = acc[i][j][r];
  }
  __syncthreads();
  if (kh == 0) {
#pragma unroll
    for (int i = 0; i < 2; ++i)
#pragma unroll
      for (int j = 0; j < 2; ++j)
#pragma unroll
        for (int r = 0; r < 16; ++r)
          acc[i][j][r] += red[(((wq * 2 + i) * 2 + j) << 10) + (r << 6) + lane];
    // fused epilogue: Yt = sigQ * num / den
    const int colh = wc * 32 + (lane & 31);
    const int rbase = (lane >> 5) * 4;
#pragma unroll
    for (int i = 0; i < 2; ++i) {
      const int tb = m0 + wr * 64 + i * 32;
#pragma unroll
      for (int r = 0; r < 16; ++r) {
        const int trow = tb + (r & 3) + 8 * (r >> 2) + rbase;
        const size_t mrow = (size_t)b * 4096 + trow;
        const float num = acc[i][0][r];
        const float den = acc[i][1][r];
        const float sq = (float)sigQ[mrow * 64 + colh];
        Yt[mrow * 64 + colh] = (f16)(sq * num / den);
      }
    }
  }
}

// ---------------- k4_out: out[m][d] = Yt @ wp^T + bp (f32 out) ----------------
__global__ __launch_bounds__(256) void k4_out(const f16* __restrict__ Yt,
                                              const f16* __restrict__ wpb,
                                              const float* __restrict__ bp,
                                              float* __restrict__ out) {
  __shared__ alignas(16) f16 sA[128 * 64];
  __shared__ alignas(16) f16 sB[128 * 64];
  const int tid = threadIdx.x;
  const int wave = tid >> 6, lane = tid & 63;
  const int m0 = blockIdx.x * 128;  // 256
  const int n0 = blockIdx.y * 128;  // 4
  const int wm = (wave >> 1) * 64;
  const int wn = (wave & 1) * 64;
  const int l15 = lane & 15;
  const int sc8 = tid & 7;
  const int scol = (sc8 ^ ((tid >> 3) & 7)) * 8;

#pragma unroll
  for (int q = 0; q < 4; ++q) {
    int r = q * 32 + (tid >> 3);
    gld16(Yt + (size_t)(m0 + r) * 64 + scol, &sA[r * 64 + sc8 * 8]);
    gld16(wpb + (size_t)(n0 + r) * 64 + scol, &sB[r * 64 + sc8 * 8]);
  }
  __syncthreads();

  f32x4 acc[4][4];
#pragma unroll
  for (int i = 0; i < 4; ++i)
#pragma unroll
    for (int j = 0; j < 4; ++j) acc[i][j] = (f32x4){0.f, 0.f, 0.f, 0.f};

#pragma unroll
  for (int kk = 0; kk < 2; ++kk) {
    const int c = kk * 4 + (lane >> 4);
    f16x8 af[4], bfr[4];
#pragma unroll
    for (int i = 0; i < 4; ++i) {
      const int r = wm + i * 16 + l15;
      af[i] = *(const f16x8*)&sA[r * 64 + ((c ^ (r & 7)) * 8)];
    }
#pragma unroll
    for (int j = 0; j < 4; ++j) {
      const int r = wn + j * 16 + l15;
      bfr[j] = *(const f16x8*)&sB[r * 64 + ((c ^ (r & 7)) * 8)];
    }
#pragma unroll
    for (int i = 0; i < 4; ++i)
#pragma unroll
      for (int j = 0; j < 4; ++j) acc[i][j] = MFMA16(af[i], bfr[j], acc[i][j]);
  }

#pragma unroll
  for (int i = 0; i < 4; ++i) {
    const int row = m0 + wm + i * 16 + (lane >> 4) * 4;
#pragma unroll
    for (int j = 0; j < 4; ++j) {
      const int col = n0 + wn + j * 16 + l15;
      const float bpv = bp[col];
#pragma unroll
      for (int r = 0; r < 4; ++r)
        out[(size_t)(row + r) * 512 + col] = acc[i][j][r] + bpv;
    }
  }
}

extern "C" void kernel_launch(void* const* d_in, const int* in_sizes, int n_in,
                              void* d_out, int out_size, void* d_ws, size_t ws_size,
                              hipStream_t stream) {
  const float* x = (const float*)d_in[0];
  const float* wq = (const float*)d_in[1];
  const float* bq = (const float*)d_in[2];
  const float* wk = (const float*)d_in[3];
  const float* bk = (const float*)d_in[4];
  const float* wv = (const float*)d_in[5];
  const float* bv = (const float*)d_in[6];
  const float* wp = (const float*)d_in[7];
  const float* bp = (const float*)d_in[8];
  const float* wbias = (const float*)d_in[9];
  float* out = (float*)d_out;

  char* ws = (char*)d_ws;
  f16* ew = (f16*)(ws);                  // 33,554,432 B
  f16* XT = (f16*)(ws + 33554432);       //  8,388,608 B
  f16* sigQ = (f16*)(ws + 41943040);     //  4,194,304 B
  f16* Yt = (f16*)(ws + 46137344);       //  4,194,304 B
  f16* wqkvb = (f16*)(ws + 50331648);    //    196,608 B
  f16* wpb = (f16*)(ws + 50528256);      //     65,536 B (end 50,593,792)

  prep_ew<<<4096, 256, 0, stream>>>(wbias, ew);
  prep_w<<<128, 256, 0, stream>>>(wq, wk, wv, wp, wqkvb, wpb);
  k1_qkv<<<512, 256, 0, stream>>>(x, wqkvb, bq, bk, bv, sigQ, XT);
  k2_big<<<256, 512, 0, stream>>>(ew, XT, sigQ, Yt);
  k4_out<<<dim3(256, 4), 256, 0, stream>>>(Yt, wpb, bp, out);
}

// Round 3
// 97.301 us; speedup vs baseline: 1.7519x; 1.2121x over previous
//
#include <hip/hip_runtime.h>
#include <math.h>

typedef _Float16 f16;
typedef __attribute__((ext_vector_type(8))) _Float16 f16x8;
typedef __attribute__((ext_vector_type(4))) _Float16 f16x4;
typedef __attribute__((ext_vector_type(4))) float f32x4;
typedef __attribute__((ext_vector_type(16))) float f32x16;

#define MFMA16(a, b, c) __builtin_amdgcn_mfma_f32_16x16x32_f16((a), (b), (c), 0, 0, 0)
#define MFMA32(a, b, c) __builtin_amdgcn_mfma_f32_32x32x16_f16((a), (b), (c), 0, 0, 0)

__device__ __forceinline__ void gld16(const f16* g, f16* l) {
  __builtin_amdgcn_global_load_lds(
      (const __attribute__((address_space(1))) unsigned int*)g,
      (__attribute__((address_space(3))) unsigned int*)l, 16, 0, 0);
}

__device__ __forceinline__ f16x8 pack8(const float* src) {
  float4 f0 = *(const float4*)src;
  float4 f1 = *(const float4*)(src + 4);
  f16x8 v;
  v[0] = (f16)f0.x; v[1] = (f16)f0.y; v[2] = (f16)f0.z; v[3] = (f16)f0.w;
  v[4] = (f16)f1.x; v[5] = (f16)f1.y; v[6] = (f16)f1.z; v[7] = (f16)f1.w;
  return v;
}

// ---------------- prep: ew = exp(wbias) as f16 [4096][4096] ----------------
__global__ __launch_bounds__(256) void prep_ew(const float* __restrict__ wb,
                                               f16* __restrict__ ew) {
  const size_t stride = (size_t)gridDim.x * 256;
  const size_t total = (size_t)4096 * 4096 / 4;
  for (size_t i = (size_t)blockIdx.x * 256 + threadIdx.x; i < total; i += stride) {
    float4 f = ((const float4*)wb)[i];
    f16x4 o;
    o.x = (f16)expf(f.x); o.y = (f16)expf(f.y);
    o.z = (f16)expf(f.z); o.w = (f16)expf(f.w);
    ((f16x4*)ew)[i] = o;
  }
}

// ---------------- prep: cast weights to f16 ----------------
// wqkvb [192][512]: rows 0-63 = wk, 64-127 = wv, 128-191 = wq. wpb [512][64].
__global__ __launch_bounds__(256) void prep_w(const float* __restrict__ wq,
                                              const float* __restrict__ wk,
                                              const float* __restrict__ wv,
                                              const float* __restrict__ wp,
                                              f16* __restrict__ wqkvb,
                                              f16* __restrict__ wpb) {
  int i = blockIdx.x * 256 + threadIdx.x;  // grid = 128 -> i in [0, 32768)
  wqkvb[i] = (f16)wk[i];
  wqkvb[32768 + i] = (f16)wv[i];
  wqkvb[65536 + i] = (f16)wq[i];
  wpb[i] = (f16)wp[i];
}

// ---------------- k1_qkv: sigQ[m][h], XT[b*128+h][t]=eK*V, XT[b*128+64+h][t]=eK --------
__global__ __launch_bounds__(256) void k1_qkv(const float* __restrict__ x,
                                              const f16* __restrict__ wqkvb,
                                              const float* __restrict__ bq,
                                              const float* __restrict__ bk,
                                              const float* __restrict__ bv,
                                              f16* __restrict__ sigQ,
                                              f16* __restrict__ XT) {
  __shared__ alignas(16) f16 sW[192 * 64];
  __shared__ alignas(16) f16 sX[64 * 64];
  const int tid = threadIdx.x;
  const int wave = tid >> 6, lane = tid & 63;
  const int m0 = blockIdx.x * 64;
  const int l15 = lane & 15;

  f32x4 accQ[4], accK[4], accV[4];
#pragma unroll
  for (int j = 0; j < 4; ++j) {
    accQ[j] = (f32x4){0.f, 0.f, 0.f, 0.f};
    accK[j] = (f32x4){0.f, 0.f, 0.f, 0.f};
    accV[j] = (f32x4){0.f, 0.f, 0.f, 0.f};
  }

  const int sc8 = tid & 7;
  const int wr8 = (tid >> 3) & 7;
  const int wcol = (sc8 ^ wr8) * 8;  // swizzled source col (elements)

  for (int ks = 0; ks < 512; ks += 64) {
#pragma unroll
    for (int q = 0; q < 6; ++q) {
      int r = q * 32 + (tid >> 3);
      gld16(wqkvb + (size_t)r * 512 + ks + wcol, &sW[r * 64 + sc8 * 8]);
    }
#pragma unroll
    for (int u = 0; u < 2; ++u) {
      int un = tid + u * 256;
      int r = un >> 3, c8 = un & 7;
      *(f16x8*)&sX[r * 64 + ((c8 ^ (r & 7)) * 8)] =
          pack8(x + (size_t)(m0 + r) * 512 + ks + c8 * 8);
    }
    __syncthreads();
#pragma unroll
    for (int kk = 0; kk < 2; ++kk) {
      const int c = kk * 4 + (lane >> 4);
      const int rK = wave * 16 + l15;
      const int rV = 64 + rK;
      f16x8 aK = *(const f16x8*)&sW[rK * 64 + ((c ^ (rK & 7)) * 8)];
      f16x8 aV = *(const f16x8*)&sW[rV * 64 + ((c ^ (rV & 7)) * 8)];
      f16x8 aQ = *(const f16x8*)&sX[rK * 64 + ((c ^ (rK & 7)) * 8)];
#pragma unroll
      for (int j = 0; j < 4; ++j) {
        const int rX = j * 16 + l15;
        const int rWq = 128 + j * 16 + l15;
        f16x8 bx = *(const f16x8*)&sX[rX * 64 + ((c ^ (rX & 7)) * 8)];
        f16x8 bw = *(const f16x8*)&sW[rWq * 64 + ((c ^ (rWq & 7)) * 8)];
        accK[j] = MFMA16(aK, bx, accK[j]);
        accV[j] = MFMA16(aV, bx, accV[j]);
        accQ[j] = MFMA16(aQ, bw, accQ[j]);
      }
    }
    __syncthreads();
  }
  const int b = m0 >> 12, t0 = m0 & 4095;
#pragma unroll
  for (int j = 0; j < 4; ++j) {
    const int h = j * 16 + l15;
    const float bqv = bq[h];
#pragma unroll
    for (int r = 0; r < 4; ++r) {
      const int m = m0 + wave * 16 + (lane >> 4) * 4 + r;
      const float v = accQ[j][r] + bqv;
      sigQ[(size_t)m * 64 + h] = (f16)(1.f / (1.f + expf(-v)));
    }
  }
#pragma unroll
  for (int r = 0; r < 4; ++r) {
    const int h = wave * 16 + (lane >> 4) * 4 + r;
    const float bkv = bk[h], bvv = bv[h];
    const size_t rowKV = (size_t)(b * 128 + h) * 4096;
    const size_t rowK = (size_t)(b * 128 + 64 + h) * 4096;
#pragma unroll
    for (int j = 0; j < 4; ++j) {
      const int t = t0 + j * 16 + l15;
      const float ek = expf(accK[j][r] + bkv);
      const float ev = accV[j][r] + bvv;
      XT[rowKV + t] = (f16)(ek * ev);
      XT[rowK + t] = (f16)ek;
    }
  }
}

// ---------------- k2_big: Yt = sigQ * (ew@num^T)/(ew@den^T), fused ----------------
// 512 thr, 8 waves, BM=128 x BN=128 (one batch: 64 num + 64 den), BK=128,
// in-block K-split (waves 0-3 / 4-7), wave tile 64x64 via MFMA32.
// Counted-vmcnt double-buffer pipeline (T4); XOR-16 swizzle both sides (T2);
// XCD mapping: all 8 batches of an m-tile on one XCD (ew panel L2-filled once).
__global__ __launch_bounds__(512) void k2_big(const f16* __restrict__ A,
                                              const f16* __restrict__ Bm,
                                              const f16* __restrict__ sigQ,
                                              f16* __restrict__ Yt) {
  __shared__ alignas(16) f16 sA[2][128 * 128];
  __shared__ alignas(16) f16 sB[2][128 * 128];
  const int tid = threadIdx.x;
  const int wave = tid >> 6, lane = tid & 63;
  const int kh = wave >> 2;            // k-half
  const int wq = wave & 3;
  const int wr = wq >> 1, wc = wq & 1;
  const int bid = blockIdx.x;
  const int b = (bid >> 3) & 7;                    // batch
  const int m0 = ((bid & 7) + 8 * (bid >> 6)) * 128;  // same-m blocks share XCD
  const f16* Bbase = Bm + (size_t)(b * 128) * 4096;

  const int srow = tid >> 4;           // 0..31
  const int sc16 = tid & 15;           // chunk 0..15
  const int gcol = (sc16 ^ (srow & 15)) * 8;  // pre-swizzled source col (XOR-16)

  f32x16 acc[2][2];
#pragma unroll
  for (int i = 0; i < 2; ++i)
#pragma unroll
    for (int j = 0; j < 2; ++j)
#pragma unroll
      for (int r = 0; r < 16; ++r) acc[i][j][r] = 0.f;

#define K2_STAGE(buf, ks)                                                              \
  do {                                                                                 \
    _Pragma("unroll") for (int q = 0; q < 4; ++q) {                                    \
      int r = q * 32 + srow;                                                           \
      gld16(A + (size_t)(m0 + r) * 4096 + (ks) + gcol, &sA[buf][r * 128 + sc16 * 8]);  \
      gld16(Bbase + (size_t)r * 4096 + (ks) + gcol, &sB[buf][r * 128 + sc16 * 8]);     \
    }                                                                                  \
  } while (0)

  K2_STAGE(0, 0);
  K2_STAGE(1, 128);
  asm volatile("s_waitcnt vmcnt(8)" ::: "memory");  // tile 0's 8 loads landed
  __builtin_amdgcn_s_barrier();
  asm volatile("" ::: "memory");

  const int rA0 = wr * 64 + (lane & 31);
  const int rB0 = wc * 32 + (lane & 31);
  const int l15x = lane & 15;          // == row&15 for all frag rows
  const int nk = 4096 / 128;
  for (int t = 0; t < nk; ++t) {
    const int buf = t & 1;
#pragma unroll
    for (int kk = 0; kk < 4; ++kk) {
      const int c = kh * 8 + kk * 2 + (lane >> 5);
      const int cx = (c ^ l15x) * 8;
      f16x8 a0 = *(const f16x8*)&sA[buf][rA0 * 128 + cx];
      f16x8 a1 = *(const f16x8*)&sA[buf][(rA0 + 32) * 128 + cx];
      f16x8 b0 = *(const f16x8*)&sB[buf][rB0 * 128 + cx];
      f16x8 b1 = *(const f16x8*)&sB[buf][(rB0 + 64) * 128 + cx];
      acc[0][0] = MFMA32(a0, b0, acc[0][0]);
      acc[0][1] = MFMA32(a0, b1, acc[0][1]);
      acc[1][0] = MFMA32(a1, b0, acc[1][0]);
      acc[1][1] = MFMA32(a1, b1, acc[1][1]);
    }
    if (t + 1 < nk) {
      asm volatile("s_waitcnt lgkmcnt(0)" ::: "memory");
      __builtin_amdgcn_s_barrier();              // all waves done reading buf
      asm volatile("" ::: "memory");
      if (t + 2 < nk) {
        K2_STAGE(buf, (t + 2) * 128);            // overwrite buf with tile t+2
        asm volatile("s_waitcnt vmcnt(8)" ::: "memory");  // tile t+1 landed
      } else {
        asm volatile("s_waitcnt vmcnt(0)" ::: "memory");
      }
      __builtin_amdgcn_s_barrier();              // tile t+1 ready
      asm volatile("" ::: "memory");
    }
  }
#undef K2_STAGE

  __syncthreads();
  // merge k-halves through LDS (reuse sA region: 16 tiles x 4KB = 64KB)
  float* red = (float*)sA;
  if (kh == 1) {
#pragma unroll
    for (int i = 0; i < 2; ++i)
#pragma unroll
      for (int j = 0; j < 2; ++j)
#pragma unroll
        for (int r = 0; r < 16; ++r)
          red[(((wq * 2 + i) * 2 + j) << 10) + (r << 6) + lane] = acc[i][j][r];
  }
  __syncthreads();
  if (kh == 0) {
#pragma unroll
    for (int i = 0; i < 2; ++i)
#pragma unroll
      for (int j = 0; j < 2; ++j)
#pragma unroll
        for (int r = 0; r < 16; ++r)
          acc[i][j][r] += red[(((wq * 2 + i) * 2 + j) << 10) + (r << 6) + lane];
    // fused epilogue: Yt = sigQ * num / den
    const int colh = wc * 32 + (lane & 31);
    const int rbase = (lane >> 5) * 4;
#pragma unroll
    for (int i = 0; i < 2; ++i) {
      const int tb = m0 + wr * 64 + i * 32;
#pragma unroll
      for (int r = 0; r < 16; ++r) {
        const int trow = tb + (r & 3) + 8 * (r >> 2) + rbase;
        const size_t mrow = (size_t)b * 4096 + trow;
        const float num = acc[i][0][r];
        const float den = acc[i][1][r];
        const float sq = (float)sigQ[mrow * 64 + colh];
        Yt[mrow * 64 + colh] = (f16)(sq * num / den);
      }
    }
  }
}

// ---------------- k4_out: out[m][d] = Yt @ wp^T + bp (f32 out) ----------------
__global__ __launch_bounds__(256) void k4_out(const f16* __restrict__ Yt,
                                              const f16* __restrict__ wpb,
                                              const float* __restrict__ bp,
                                              float* __restrict__ out) {
  __shared__ alignas(16) f16 sA[128 * 64];
  __shared__ alignas(16) f16 sB[128 * 64];
  const int tid = threadIdx.x;
  const int wave = tid >> 6, lane = tid & 63;
  const int m0 = blockIdx.x * 128;  // 256
  const int n0 = blockIdx.y * 128;  // 4
  const int wm = (wave >> 1) * 64;
  const int wn = (wave & 1) * 64;
  const int l15 = lane & 15;
  const int sc8 = tid & 7;
  const int scol = (sc8 ^ ((tid >> 3) & 7)) * 8;

#pragma unroll
  for (int q = 0; q < 4; ++q) {
    int r = q * 32 + (tid >> 3);
    gld16(Yt + (size_t)(m0 + r) * 64 + scol, &sA[r * 64 + sc8 * 8]);
    gld16(wpb + (size_t)(n0 + r) * 64 + scol, &sB[r * 64 + sc8 * 8]);
  }
  __syncthreads();

  f32x4 acc[4][4];
#pragma unroll
  for (int i = 0; i < 4; ++i)
#pragma unroll
    for (int j = 0; j < 4; ++j) acc[i][j] = (f32x4){0.f, 0.f, 0.f, 0.f};

#pragma unroll
  for (int kk = 0; kk < 2; ++kk) {
    const int c = kk * 4 + (lane >> 4);
    f16x8 af[4], bfr[4];
#pragma unroll
    for (int i = 0; i < 4; ++i) {
      const int r = wm + i * 16 + l15;
      af[i] = *(const f16x8*)&sA[r * 64 + ((c ^ (r & 7)) * 8)];
    }
#pragma unroll
    for (int j = 0; j < 4; ++j) {
      const int r = wn + j * 16 + l15;
      bfr[j] = *(const f16x8*)&sB[r * 64 + ((c ^ (r & 7)) * 8)];
    }
#pragma unroll
    for (int i = 0; i < 4; ++i)
#pragma unroll
      for (int j = 0; j < 4; ++j) acc[i][j] = MFMA16(af[i], bfr[j], acc[i][j]);
  }

#pragma unroll
  for (int i = 0; i < 4; ++i) {
    const int row = m0 + wm + i * 16 + (lane >> 4) * 4;
#pragma unroll
    for (int j = 0; j < 4; ++j) {
      const int col = n0 + wn + j * 16 + l15;
      const float bpv = bp[col];
#pragma unroll
      for (int r = 0; r < 4; ++r)
        out[(size_t)(row + r) * 512 + col] = acc[i][j][r] + bpv;
    }
  }
}

extern "C" void kernel_launch(void* const* d_in, const int* in_sizes, int n_in,
                              void* d_out, int out_size, void* d_ws, size_t ws_size,
                              hipStream_t stream) {
  const float* x = (const float*)d_in[0];
  const float* wq = (const float*)d_in[1];
  const float* bq = (const float*)d_in[2];
  const float* wk = (const float*)d_in[3];
  const float* bk = (const float*)d_in[4];
  const float* wv = (const float*)d_in[5];
  const float* bv = (const float*)d_in[6];
  const float* wp = (const float*)d_in[7];
  const float* bp = (const float*)d_in[8];
  const float* wbias = (const float*)d_in[9];
  float* out = (float*)d_out;

  char* ws = (char*)d_ws;
  f16* ew = (f16*)(ws);                  // 33,554,432 B
  f16* XT = (f16*)(ws + 33554432);       //  8,388,608 B
  f16* sigQ = (f16*)(ws + 41943040);     //  4,194,304 B
  f16* Yt = (f16*)(ws + 46137344);       //  4,194,304 B
  f16* wqkvb = (f16*)(ws + 50331648);    //    196,608 B
  f16* wpb = (f16*)(ws + 50528256);      //     65,536 B (end 50,593,792)

  prep_ew<<<4096, 256, 0, stream>>>(wbias, ew);
  prep_w<<<128, 256, 0, stream>>>(wq, wk, wv, wp, wqkvb, wpb);
  k1_qkv<<<512, 256, 0, stream>>>(x, wqkvb, bq, bk, bv, sigQ, XT);
  k2_big<<<256, 512, 0, stream>>>(ew, XT, sigQ, Yt);
  k4_out<<<dim3(256, 4), 256, 0, stream>>>(Yt, wpb, bp, out);
}